// Round 1
// baseline (375.464 us; speedup 1.0000x reference)
//
#include <hip/hip_runtime.h>

#define NN   100000
#define KD   500
#define HID  64

// ---------------- Kernel 1: h = relu(x @ W1^T) ----------------
// block 256, tile 64 rows x 64 cols, K staged in 5 chunks of 100.
// LDS: x and W1 chunks stored transposed [k][row] for vector compute reads.
__global__ __launch_bounds__(256) void k1_gemm_relu(const float* __restrict__ x,
                                                    const float* __restrict__ W1,
                                                    float* __restrict__ h, int n)
{
    __shared__ float lx[100][68];
    __shared__ float lw[100][68];
    const int tid = threadIdx.x;
    const int cg  = tid & 15;   // 16 col-groups of 4 cols
    const int rg  = tid >> 4;   // 16 row-groups of 4 rows
    const long r0 = (long)blockIdx.x * 64;

    float acc[4][4] = {};

    for (int kc = 0; kc < 5; ++kc) {
        const int k0 = kc * 100;
        // stage x tile (64 rows x 100 k) and W1 tile (64 cols x 100 k), transposed
        for (int idx = tid; idx < 3200; idx += 256) {
            const bool isW = idx >= 1600;
            const int  id2 = isW ? (idx - 1600) : idx;
            const int  r   = id2 / 25;        // 0..63
            const int  q   = id2 - r * 25;    // 0..24 (float4 index)
            const float* srcp;
            if (!isW) {
                long rowg = r0 + r;
                if (rowg >= n) rowg = n - 1;  // clamp (stores are guarded)
                srcp = x + rowg * KD + (k0 + 4 * q);
            } else {
                srcp = W1 + (long)r * KD + (k0 + 4 * q);
            }
            const float4 v = *(const float4*)srcp;
            float* dbase = isW ? &lw[0][0] : &lx[0][0];
            dbase[(4*q + 0) * 68 + r] = v.x;
            dbase[(4*q + 1) * 68 + r] = v.y;
            dbase[(4*q + 2) * 68 + r] = v.z;
            dbase[(4*q + 3) * 68 + r] = v.w;
        }
        __syncthreads();
        #pragma unroll 2
        for (int k = 0; k < 100; ++k) {
            const float4 xa = *(const float4*)&lx[k][rg * 4];
            const float4 wb = *(const float4*)&lw[k][cg * 4];
            const float xr[4] = {xa.x, xa.y, xa.z, xa.w};
            const float wc[4] = {wb.x, wb.y, wb.z, wb.w};
            #pragma unroll
            for (int i = 0; i < 4; ++i)
                #pragma unroll
                for (int j = 0; j < 4; ++j)
                    acc[i][j] = fmaf(xr[i], wc[j], acc[i][j]);
        }
        __syncthreads();
    }

    #pragma unroll
    for (int i = 0; i < 4; ++i) {
        const long rowg = r0 + rg * 4 + i;
        if (rowg < n) {
            float4 o;
            o.x = fmaxf(acc[i][0], 0.f);
            o.y = fmaxf(acc[i][1], 0.f);
            o.z = fmaxf(acc[i][2], 0.f);
            o.w = fmaxf(acc[i][3], 0.f);
            *(float4*)&h[rowg * HID + cg * 4] = o;
        }
    }
}

// ---------------- Kernel 2: projections ----------------
// out_partial = h @ WfA^T  (written to d_out)
// g[:,0:10]  = h @ WfB^T   (gb)
// g[:,10:20] = h @ WfC^T   (gc)
// block 256 = 8 rows x 32 j-slots (30 active)
__global__ __launch_bounds__(256) void k2_proj(const float* __restrict__ h,
                                               const float* __restrict__ Wf,
                                               float* __restrict__ out,
                                               float* __restrict__ g, int n)
{
    __shared__ float lwf[10 * 196];  // padded row stride 196 (bank spread)
    const int tid = threadIdx.x;
    for (int idx = tid; idx < 480; idx += 256) {   // 1920 floats as float4
        const int j = idx / 48;
        const int q = idx - j * 48;
        const float4 v = *(const float4*)&Wf[j * 192 + 4 * q];
        *(float4*)&lwf[j * 196 + 4 * q] = v;
    }
    __syncthreads();

    const long row = (long)blockIdx.x * 8 + (tid >> 5);
    const int  j   = tid & 31;
    if (row < n && j < 30) {
        const int wrow = (j < 10) ? j : ((j < 20) ? j - 10 : j - 20);
        const int coff = (j < 10) ? 0 : ((j < 20) ? 64 : 128);
        const float* wp = &lwf[wrow * 196 + coff];
        const float* hp = &h[row * HID];
        float s = 0.f;
        #pragma unroll
        for (int q = 0; q < 16; ++q) {
            const float4 hv = *(const float4*)&hp[4 * q];
            const float4 wv = *(const float4*)&wp[4 * q];
            s += hv.x * wv.x + hv.y * wv.y + hv.z * wv.z + hv.w * wv.w;
        }
        if (j < 10) out[row * 10 + j] = s;
        else        g[row * 20 + (j - 10)] = s;
    }
}

// ---------------- Kernel 3/4: edge scatter ----------------
// out[dst,j] += val * g[src, goff+j],  one thread per (edge, j<10)
__global__ __launch_bounds__(256) void k_scatter(const int* __restrict__ src,
                                                 const int* __restrict__ dst,
                                                 const float* __restrict__ val,
                                                 const float* __restrict__ g,
                                                 float* __restrict__ out,
                                                 int nnz, int goff)
{
    const int t = blockIdx.x * 256 + threadIdx.x;
    if (t >= nnz * 10) return;
    const int e = t / 10;
    const int j = t - e * 10;
    const int s = src[e];
    const int d = dst[e];
    const float v = val[e];
    unsafeAtomicAdd(&out[(size_t)d * 10 + j], v * g[(size_t)s * 20 + goff + j]);
}

extern "C" void kernel_launch(void* const* d_in, const int* in_sizes, int n_in,
                              void* d_out, int out_size, void* d_ws, size_t ws_size,
                              hipStream_t stream)
{
    const float* x    = (const float*)d_in[0];
    const float* W1   = (const float*)d_in[1];
    const float* Wf   = (const float*)d_in[2];
    const int*   src1 = (const int*)d_in[3];
    const int*   dst1 = (const int*)d_in[4];
    const float* val1 = (const float*)d_in[5];
    const int*   src2 = (const int*)d_in[6];
    const int*   dst2 = (const int*)d_in[7];
    const float* val2 = (const float*)d_in[8];
    const int nnz1 = in_sizes[3];
    const int nnz2 = in_sizes[6];
    const int n = NN;

    float* h = (float*)d_ws;                 // [NN][64]  = 25.6 MB
    float* g = h + (size_t)NN * HID;         // [NN][20]  =  8.0 MB
    float* out = (float*)d_out;              // [NN][10]

    k1_gemm_relu<<<(n + 63) / 64, 256, 0, stream>>>(x, W1, h, n);
    k2_proj<<<(n + 7) / 8, 256, 0, stream>>>(h, Wf, out, g, n);
    k_scatter<<<(nnz1 * 10 + 255) / 256, 256, 0, stream>>>(src1, dst1, val1, g, out, nnz1, 0);
    k_scatter<<<(nnz2 * 10 + 255) / 256, 256, 0, stream>>>(src2, dst2, val2, g, out, nnz2, 10);
}

// Round 2
// 257.056 us; speedup vs baseline: 1.4606x; 1.4606x over previous
//
#include <hip/hip_runtime.h>
#include <hip/hip_bf16.h>

#define NN   100000
#define KD   500
#define HID  64
#define LWS  264   // LDS row stride in bf16 elems: 528 B = 33 granules -> adjacent banks per row

typedef short frag8 __attribute__((ext_vector_type(8)));
typedef float f32x4 __attribute__((ext_vector_type(4)));

static __device__ __forceinline__ unsigned short f2b(float f) {
    return __builtin_bit_cast(unsigned short, __float2bfloat16(f));
}

// ---------------- Kernel 1: h = relu(x @ W1^T), bf16 MFMA ----------------
// 256 threads = 4 waves; wave computes 32 rows x 64 cols; block = 128 rows.
// W1 staged in LDS as bf16 (two K-chunks of 256, zero-padded past k=500).
// x loaded global->reg per MFMA fragment layout, converted fp32->bf16 in-reg.
__global__ __launch_bounds__(256, 4) void k1_mfma(const float* __restrict__ x,
                                                  const float* __restrict__ W1,
                                                  float* __restrict__ h, int n)
{
    __shared__ unsigned short lw[64 * LWS];
    const int tid   = threadIdx.x;
    const int lane  = tid & 63;
    const int wid   = tid >> 6;
    const int l15   = lane & 15;
    const int l4    = lane >> 4;     // 0..3
    const int koffl = 8 * l4;        // lane's k sub-offset within a 32-k step

    const long rowBlk = (long)blockIdx.x * 128 + wid * 32;
    long ra0 = rowBlk + l15;       if (ra0 >= n) ra0 = n - 1;
    long ra1 = rowBlk + 16 + l15;  if (ra1 >= n) ra1 = n - 1;
    const float* xp0 = x + ra0 * KD + koffl;
    const float* xp1 = x + ra1 * KD + koffl;

    f32x4 acc[2][4] = {};

    for (int c = 0; c < 2; ++c) {
        if (c) __syncthreads();
        // stage W1[64][c*256 .. +256) as bf16, zero-pad k >= 500
        for (int it = 0; it < 16; ++it) {
            const int idx = tid + it * 256;   // 0..4095
            const int r   = idx >> 6;         // 0..63
            const int q   = idx & 63;         // float4 index in chunk row
            const int kg  = c * 256 + 4 * q;
            float4 v = make_float4(0.f, 0.f, 0.f, 0.f);
            if (kg < KD) v = *(const float4*)&W1[(long)r * KD + kg];
            ushort4 pk;
            pk.x = f2b(v.x); pk.y = f2b(v.y); pk.z = f2b(v.z); pk.w = f2b(v.w);
            *(ushort4*)&lw[r * LWS + 4 * q] = pk;
        }
        __syncthreads();

        #pragma unroll 2
        for (int ks = 0; ks < 8; ++ks) {
            const int k0 = c * 256 + ks * 32;  // global k base of this step
            const int kb = k0 + koffl;         // lane's k base (mult of 8)
            const float4 z = make_float4(0.f, 0.f, 0.f, 0.f);
            const float4 lo0 = (kb     < KD) ? *(const float4*)(xp0 + k0)     : z;
            const float4 hi0 = (kb + 4 < KD) ? *(const float4*)(xp0 + k0 + 4) : z;
            const float4 lo1 = (kb     < KD) ? *(const float4*)(xp1 + k0)     : z;
            const float4 hi1 = (kb + 4 < KD) ? *(const float4*)(xp1 + k0 + 4) : z;
            frag8 a0, a1;
            a0[0]=f2b(lo0.x); a0[1]=f2b(lo0.y); a0[2]=f2b(lo0.z); a0[3]=f2b(lo0.w);
            a0[4]=f2b(hi0.x); a0[5]=f2b(hi0.y); a0[6]=f2b(hi0.z); a0[7]=f2b(hi0.w);
            a1[0]=f2b(lo1.x); a1[1]=f2b(lo1.y); a1[2]=f2b(lo1.z); a1[3]=f2b(lo1.w);
            a1[4]=f2b(hi1.x); a1[5]=f2b(hi1.y); a1[6]=f2b(hi1.z); a1[7]=f2b(hi1.w);
            const int koffw = ks * 32 + koffl; // within-chunk k offset
            #pragma unroll
            for (int g = 0; g < 4; ++g) {
                const frag8 b = *(const frag8*)&lw[(g * 16 + l15) * LWS + koffw];
                acc[0][g] = __builtin_amdgcn_mfma_f32_16x16x32_bf16(a0, b, acc[0][g], 0, 0, 0);
                acc[1][g] = __builtin_amdgcn_mfma_f32_16x16x32_bf16(a1, b, acc[1][g], 0, 0, 0);
            }
        }
    }

    // epilogue: relu + store (D layout: col = lane&15, row = (lane>>4)*4 + reg)
    #pragma unroll
    for (int rb = 0; rb < 2; ++rb) {
        #pragma unroll
        for (int r = 0; r < 4; ++r) {
            const long row = rowBlk + rb * 16 + l4 * 4 + r;
            if (row < n) {
                #pragma unroll
                for (int g = 0; g < 4; ++g)
                    h[row * HID + g * 16 + l15] = fmaxf(acc[rb][g][r], 0.f);
            }
        }
    }
}

// ---------------- Kernel 2: projections (unchanged from passing R1) ----------------
__global__ __launch_bounds__(256) void k2_proj(const float* __restrict__ h,
                                               const float* __restrict__ Wf,
                                               float* __restrict__ out,
                                               float* __restrict__ g, int n)
{
    __shared__ float lwf[10 * 196];
    const int tid = threadIdx.x;
    for (int idx = tid; idx < 480; idx += 256) {
        const int j = idx / 48;
        const int q = idx - j * 48;
        const float4 v = *(const float4*)&Wf[j * 192 + 4 * q];
        *(float4*)&lwf[j * 196 + 4 * q] = v;
    }
    __syncthreads();

    const long row = (long)blockIdx.x * 8 + (tid >> 5);
    const int  j   = tid & 31;
    if (row < n && j < 30) {
        const int wrow = (j < 10) ? j : ((j < 20) ? j - 10 : j - 20);
        const int coff = (j < 10) ? 0 : ((j < 20) ? 64 : 128);
        const float* wp = &lwf[wrow * 196 + coff];
        const float* hp = &h[row * HID];
        float s = 0.f;
        #pragma unroll
        for (int q = 0; q < 16; ++q) {
            const float4 hv = *(const float4*)&hp[4 * q];
            const float4 wv = *(const float4*)&wp[4 * q];
            s += hv.x * wv.x + hv.y * wv.y + hv.z * wv.z + hv.w * wv.w;
        }
        if (j < 10) out[row * 10 + j] = s;
        else        g[row * 20 + (j - 10)] = s;
    }
}

// ---------------- Kernel 3/4: edge scatter (unchanged from passing R1) ----------------
__global__ __launch_bounds__(256) void k_scatter(const int* __restrict__ src,
                                                 const int* __restrict__ dst,
                                                 const float* __restrict__ val,
                                                 const float* __restrict__ g,
                                                 float* __restrict__ out,
                                                 int nnz, int goff)
{
    const int t = blockIdx.x * 256 + threadIdx.x;
    if (t >= nnz * 10) return;
    const int e = t / 10;
    const int j = t - e * 10;
    const int s = src[e];
    const int d = dst[e];
    const float v = val[e];
    unsafeAtomicAdd(&out[(size_t)d * 10 + j], v * g[(size_t)s * 20 + goff + j]);
}

extern "C" void kernel_launch(void* const* d_in, const int* in_sizes, int n_in,
                              void* d_out, int out_size, void* d_ws, size_t ws_size,
                              hipStream_t stream)
{
    const float* x    = (const float*)d_in[0];
    const float* W1   = (const float*)d_in[1];
    const float* Wf   = (const float*)d_in[2];
    const int*   src1 = (const int*)d_in[3];
    const int*   dst1 = (const int*)d_in[4];
    const float* val1 = (const float*)d_in[5];
    const int*   src2 = (const int*)d_in[6];
    const int*   dst2 = (const int*)d_in[7];
    const float* val2 = (const float*)d_in[8];
    const int nnz1 = in_sizes[3];
    const int nnz2 = in_sizes[6];
    const int n = NN;

    float* h = (float*)d_ws;                 // [NN][64]  = 25.6 MB
    float* g = h + (size_t)NN * HID;         // [NN][20]  =  8.0 MB
    float* out = (float*)d_out;              // [NN][10]

    k1_mfma<<<(n + 127) / 128, 256, 0, stream>>>(x, W1, h, n);
    k2_proj<<<(n + 7) / 8, 256, 0, stream>>>(h, Wf, out, g, n);
    k_scatter<<<(nnz1 * 10 + 255) / 256, 256, 0, stream>>>(src1, dst1, val1, g, out, nnz1, 0);
    k_scatter<<<(nnz2 * 10 + 255) / 256, 256, 0, stream>>>(src2, dst2, val2, g, out, nnz2, 10);
}